// Round 2
// baseline (830.559 us; speedup 1.0000x reference)
//
#include <hip/hip_runtime.h>
#include <math.h>

#define N_NODES 20000
#define N_EDGES 160000

#define PI_F 3.14159265358979323846f
#define LN2_F 0.69314718055994530942f

__device__ __forceinline__ float sspf(float x) {
    return fmaxf(x, 0.0f) + log1pf(expf(-fabsf(x))) - LN2_F;
}
__device__ __forceinline__ void fma4(float4& a, float s, const float4& w) {
    a.x = fmaf(s, w.x, a.x); a.y = fmaf(s, w.y, a.y);
    a.z = fmaf(s, w.z, a.z); a.w = fmaf(s, w.w, a.w);
}
// round-to-nearest-even f32 -> bf16 (bit trick)
__device__ __forceinline__ unsigned short f2bf(float f) {
    unsigned int u = __float_as_uint(f);
    return (unsigned short)((u + 0x7fffu + ((u >> 16) & 1u)) >> 16);
}
__device__ __forceinline__ float bflo(unsigned int u) { return __uint_as_float(u << 16); }
__device__ __forceinline__ float bfhi(unsigned int u) { return __uint_as_float(u & 0xffff0000u); }

// ---------------------------------------------------------------------------
// rb_sw[e][n] = switch[e] * sqrt(2/5) * sin((n+1) pi r / 5) / r   (E x 8)
// ---------------------------------------------------------------------------
__global__ __launch_bounds__(256) void edge_rb_kernel(
    const float* __restrict__ dist,
    const float* __restrict__ sw,
    float* __restrict__ rb)
{
    int e = blockIdx.x * blockDim.x + threadIdx.x;
    if (e >= N_EDGES) return;
    float r = dist[e];
    float c = sqrtf(2.0f / 5.0f) / r * sw[e];
    float out[8];
    #pragma unroll
    for (int n = 0; n < 8; ++n)
        out[n] = c * sinf((float)(n + 1) * PI_F * r * 0.2f);
    float4* p = reinterpret_cast<float4*>(rb + (size_t)e * 8);
    p[0] = make_float4(out[0], out[1], out[2], out[3]);
    p[1] = make_float4(out[4], out[5], out[6], out[7]);
}

// ---------------------------------------------------------------------------
// CSR offsets from sorted edge_src
// ---------------------------------------------------------------------------
__global__ __launch_bounds__(256) void row_start_kernel(
    const int* __restrict__ src, int* __restrict__ row)
{
    int i = blockIdx.x * blockDim.x + threadIdx.x;
    if (i > N_NODES) return;
    int lo = 0, hi = N_EDGES;
    while (lo < hi) {
        int mid = (lo + hi) >> 1;
        if (src[mid] < i) lo = mid + 1; else hi = mid;
    }
    row[i] = lo;
}

// ---------------------------------------------------------------------------
// xi = W_species[species]
// ---------------------------------------------------------------------------
__global__ __launch_bounds__(256) void xi_init_kernel(
    const int* __restrict__ species,
    const float* __restrict__ Wsp,
    float* __restrict__ xi)
{
    int idx = blockIdx.x * blockDim.x + threadIdx.x;
    if (idx >= N_NODES * 16) return;
    int node = idx >> 4;
    int c4 = idx & 15;
    int sp = species[node];
    reinterpret_cast<float4*>(xi)[idx] =
        reinterpret_cast<const float4*>(Wsp + (size_t)sp * 64)[c4];
}

// ---------------------------------------------------------------------------
// h = xi @ Wl[l] + bl[l]   (N x 32)
// ---------------------------------------------------------------------------
__global__ __launch_bounds__(256) void h_kernel(
    const float* __restrict__ xi,
    const float* __restrict__ Wl,
    const float* __restrict__ bl,
    float* __restrict__ h)
{
    __shared__ float xs[32 * 64];
    __shared__ float ws[64 * 32];
    int tid = threadIdx.x;
    int nb = blockIdx.x * 32;

    const float4* xsrc = reinterpret_cast<const float4*>(xi + (size_t)nb * 64);
    float4* xd = reinterpret_cast<float4*>(xs);
    #pragma unroll
    for (int i = 0; i < 2; ++i) xd[tid + i * 256] = xsrc[tid + i * 256];
    const float4* wsrc = reinterpret_cast<const float4*>(Wl);
    float4* wd = reinterpret_cast<float4*>(ws);
    #pragma unroll
    for (int i = 0; i < 2; ++i) wd[tid + i * 256] = wsrc[tid + i * 256];
    __syncthreads();

    int c = tid & 31;
    int ng = tid >> 5;
    float bias = bl[c];
    float acc[4] = {bias, bias, bias, bias};
    for (int j = 0; j < 64; ++j) {
        float wv = ws[j * 32 + c];
        #pragma unroll
        for (int q = 0; q < 4; ++q)
            acc[q] = fmaf(xs[(ng * 4 + q) * 64 + j], wv, acc[q]);
    }
    #pragma unroll
    for (int q = 0; q < 4; ++q)
        h[(size_t)(nb + ng * 4 + q) * 32 + c] = acc[q];
}

// ---------------------------------------------------------------------------
// Aggregation: one wave per node. lane = (es in 0..3)<<4 | (s in 0..15).
// Each lane accumulates 40 (n,b) products for its s over edges e0+es, +4...
// Butterfly reduce over the 4 edge slots, store bf16 PERMUTED: f = s*40+n*5+b.
// ---------------------------------------------------------------------------
__global__ __launch_bounds__(256) void agg_kernel(
    const float* __restrict__ rb,    // E x 8 (includes switch factor)
    const float* __restrict__ bo,    // E x 5
    const int* __restrict__ row,     // N+1
    const int* __restrict__ dst,     // E
    const float* __restrict__ h,     // N x 32
    unsigned int* __restrict__ agg)  // N x 320 (bf16 pairs)
{
    int wid = (blockIdx.x * 256 + threadIdx.x) >> 6;  // node
    if (wid >= N_NODES) return;
    int lane = threadIdx.x & 63;
    int s = lane & 15;
    int es = lane >> 4;

    int e0 = row[wid], e1 = row[wid + 1];

    float acc[40];
    #pragma unroll
    for (int j = 0; j < 40; ++j) acc[j] = 0.0f;

    for (int e = e0 + es; e < e1; e += 4) {
        int d = dst[e];
        float mi = h[(size_t)d * 32 + 16 + s];
        float4 r0 = *reinterpret_cast<const float4*>(rb + (size_t)e * 8);
        float4 r1 = *reinterpret_cast<const float4*>(rb + (size_t)e * 8 + 4);
        const float* bp = bo + (size_t)e * 5;
        float bm0 = bp[0] * mi, bm1 = bp[1] * mi, bm2 = bp[2] * mi,
              bm3 = bp[3] * mi, bm4 = bp[4] * mi;
        float rr[8] = {r0.x, r0.y, r0.z, r0.w, r1.x, r1.y, r1.z, r1.w};
        #pragma unroll
        for (int n = 0; n < 8; ++n) {
            acc[n * 5 + 0] = fmaf(rr[n], bm0, acc[n * 5 + 0]);
            acc[n * 5 + 1] = fmaf(rr[n], bm1, acc[n * 5 + 1]);
            acc[n * 5 + 2] = fmaf(rr[n], bm2, acc[n * 5 + 2]);
            acc[n * 5 + 3] = fmaf(rr[n], bm3, acc[n * 5 + 3]);
            acc[n * 5 + 4] = fmaf(rr[n], bm4, acc[n * 5 + 4]);
        }
    }
    // reduce over the 4 edge slots (xor 16 and 32); all lanes end with full sum
    #pragma unroll
    for (int j = 0; j < 40; ++j) {
        acc[j] += __shfl_xor(acc[j], 16, 64);
        acc[j] += __shfl_xor(acc[j], 32, 64);
    }
    // lane (es,s) stores its 10 features: f = s*40 + es*10 + m
    unsigned int* outp = agg + ((size_t)wid * 640 + s * 40 + es * 10) / 2;
    #pragma unroll
    for (int m = 0; m < 5; ++m) {
        int j = es * 10 + 2 * m;
        unsigned int pk = (unsigned int)f2bf(acc[j]) |
                          ((unsigned int)f2bf(acc[j + 1]) << 16);
        outp[m] = pk;
    }
}

// ---------------------------------------------------------------------------
// FC chain: 64 nodes x 64 cols per block of 256.  Thread owns nodes {r, r+32}
// x cols [8kg, 8kg+8).  W1 rows permuted on the fly to match agg layout.
// ---------------------------------------------------------------------------
template<int NK4>
__device__ __forceinline__ void gemm_tile(
    const float* __restrict__ Xbase, const float* __restrict__ Ws,
    int r, int kg, float4& a00, float4& a01, float4& a10, float4& a11)
{
    const float* xa_p = Xbase + r * 68;
    const float* xb_p = Xbase + (r + 32) * 68;
    #pragma unroll
    for (int k4 = 0; k4 < NK4; ++k4) {
        float4 xa = *reinterpret_cast<const float4*>(xa_p + k4 * 4);
        float4 xb = *reinterpret_cast<const float4*>(xb_p + k4 * 4);
        const float4* wb = reinterpret_cast<const float4*>(Ws) + k4 * 64 + kg * 2;
        fma4(a00, xa.x, wb[0]);   fma4(a01, xa.x, wb[1]);
        fma4(a10, xb.x, wb[0]);   fma4(a11, xb.x, wb[1]);
        fma4(a00, xa.y, wb[16]);  fma4(a01, xa.y, wb[17]);
        fma4(a10, xb.y, wb[16]);  fma4(a11, xb.y, wb[17]);
        fma4(a00, xa.z, wb[32]);  fma4(a01, xa.z, wb[33]);
        fma4(a10, xb.z, wb[32]);  fma4(a11, xb.z, wb[33]);
        fma4(a00, xa.w, wb[48]);  fma4(a01, xa.w, wb[49]);
        fma4(a10, xb.w, wb[48]);  fma4(a11, xb.w, wb[49]);
    }
}

__global__ __launch_bounds__(256) void fc_kernel(
    const unsigned int* __restrict__ agg,  // bf16 pairs, N x 320
    const float* __restrict__ h,           // N x 32
    const float* __restrict__ W1, const float* __restrict__ b1,
    const float* __restrict__ W2, const float* __restrict__ b2,
    const float* __restrict__ W3, const float* __restrict__ b3,
    float* __restrict__ xi)
{
    __shared__ float Xs[64 * 68];
    __shared__ float Ws[64 * 64];
    __shared__ float Ys[64 * 68];

    int tid = threadIdx.x;
    int n0 = blockIdx.x * 64;
    int r = tid >> 3;   // 0..31
    int kg = tid & 7;   // col group

    const float4* b1f = reinterpret_cast<const float4*>(b1);
    float4 a00 = b1f[kg * 2], a01 = b1f[kg * 2 + 1];
    float4 a10 = a00, a11 = a01;

    // ---- FC1: 10 chunks of 64 features ----
    for (int c = 0; c < 10; ++c) {
        {   // stage X (bf16 -> f32)
            int rowi = tid >> 2, q = tid & 3;
            int node = n0 + rowi;
            float4 f0, f1, f2, f3;
            if (node < N_NODES) {
                const uint4* ap = reinterpret_cast<const uint4*>(
                    agg + (size_t)node * 320 + c * 32 + q * 8);
                uint4 v0 = ap[0], v1 = ap[1];
                f0 = make_float4(bflo(v0.x), bfhi(v0.x), bflo(v0.y), bfhi(v0.y));
                f1 = make_float4(bflo(v0.z), bfhi(v0.z), bflo(v0.w), bfhi(v0.w));
                f2 = make_float4(bflo(v1.x), bfhi(v1.x), bflo(v1.y), bfhi(v1.y));
                f3 = make_float4(bflo(v1.z), bfhi(v1.z), bflo(v1.w), bfhi(v1.w));
            } else {
                f0 = f1 = f2 = f3 = make_float4(0.f, 0.f, 0.f, 0.f);
            }
            float4* xd = reinterpret_cast<float4*>(Xs + rowi * 68 + q * 16);
            xd[0] = f0; xd[1] = f1; xd[2] = f2; xd[3] = f3;
        }
        // stage W chunk with row permutation rp = s*40+n*5+b -> r = n*80+s*5+b
        #pragma unroll
        for (int i = 0; i < 4; ++i) {
            int fi = tid + i * 256;
            int k = fi >> 4, col4 = fi & 15;
            int rp = c * 64 + k;
            int ss = rp / 40;
            int rem = rp - ss * 40;
            int nn = rem / 5;
            int bb = rem - nn * 5;
            int rr = nn * 80 + ss * 5 + bb;
            reinterpret_cast<float4*>(Ws)[k * 16 + col4] =
                reinterpret_cast<const float4*>(W1)[rr * 16 + col4];
        }
        __syncthreads();
        gemm_tile<16>(Xs, Ws, r, kg, a00, a01, a10, a11);
        __syncthreads();
    }
    // ---- si chunk: rows 640..655, X = h[:, :16] ----
    {
        {
            int rowi = tid >> 2, q = tid & 3;
            int node = n0 + rowi;
            float4 v = make_float4(0.f, 0.f, 0.f, 0.f);
            if (node < N_NODES)
                v = *reinterpret_cast<const float4*>(h + (size_t)node * 32 + q * 4);
            *reinterpret_cast<float4*>(Xs + rowi * 68 + q * 4) = v;
        }
        {
            int k = tid >> 4, col4 = tid & 15;
            reinterpret_cast<float4*>(Ws)[k * 16 + col4] =
                reinterpret_cast<const float4*>(W1)[(640 + k) * 16 + col4];
        }
        __syncthreads();
        gemm_tile<4>(Xs, Ws, r, kg, a00, a01, a10, a11);
        __syncthreads();
    }
    // ---- ssp -> Ys, stage W2 ----
    {
        float* yp0 = Ys + r * 68 + kg * 8;
        yp0[0] = sspf(a00.x); yp0[1] = sspf(a00.y); yp0[2] = sspf(a00.z); yp0[3] = sspf(a00.w);
        yp0[4] = sspf(a01.x); yp0[5] = sspf(a01.y); yp0[6] = sspf(a01.z); yp0[7] = sspf(a01.w);
        float* yp1 = Ys + (r + 32) * 68 + kg * 8;
        yp1[0] = sspf(a10.x); yp1[1] = sspf(a10.y); yp1[2] = sspf(a10.z); yp1[3] = sspf(a10.w);
        yp1[4] = sspf(a11.x); yp1[5] = sspf(a11.y); yp1[6] = sspf(a11.z); yp1[7] = sspf(a11.w);
    }
    #pragma unroll
    for (int i = 0; i < 4; ++i)
        reinterpret_cast<float4*>(Ws)[tid + i * 256] =
            reinterpret_cast<const float4*>(W2)[tid + i * 256];
    __syncthreads();
    // ---- FC2 ----
    {
        const float4* b2f = reinterpret_cast<const float4*>(b2);
        a00 = b2f[kg * 2]; a01 = b2f[kg * 2 + 1]; a10 = a00; a11 = a01;
        gemm_tile<16>(Ys, Ws, r, kg, a00, a01, a10, a11);
    }
    __syncthreads();
    // ---- ssp -> Ys, stage W3 ----
    {
        float* yp0 = Ys + r * 68 + kg * 8;
        yp0[0] = sspf(a00.x); yp0[1] = sspf(a00.y); yp0[2] = sspf(a00.z); yp0[3] = sspf(a00.w);
        yp0[4] = sspf(a01.x); yp0[5] = sspf(a01.y); yp0[6] = sspf(a01.z); yp0[7] = sspf(a01.w);
        float* yp1 = Ys + (r + 32) * 68 + kg * 8;
        yp1[0] = sspf(a10.x); yp1[1] = sspf(a10.y); yp1[2] = sspf(a10.z); yp1[3] = sspf(a10.w);
        yp1[4] = sspf(a11.x); yp1[5] = sspf(a11.y); yp1[6] = sspf(a11.z); yp1[7] = sspf(a11.w);
    }
    #pragma unroll
    for (int i = 0; i < 4; ++i)
        reinterpret_cast<float4*>(Ws)[tid + i * 256] =
            reinterpret_cast<const float4*>(W3)[tid + i * 256];
    __syncthreads();
    // ---- FC3 ----
    {
        const float4* b3f = reinterpret_cast<const float4*>(b3);
        a00 = b3f[kg * 2]; a01 = b3f[kg * 2 + 1]; a10 = a00; a11 = a01;
        gemm_tile<16>(Ys, Ws, r, kg, a00, a01, a10, a11);
    }
    // ---- residual update ----
    if (n0 + r < N_NODES) {
        float4* xp = reinterpret_cast<float4*>(xi + (size_t)(n0 + r) * 64 + kg * 8);
        float4 o0 = xp[0], o1 = xp[1];
        o0.x += a00.x; o0.y += a00.y; o0.z += a00.z; o0.w += a00.w;
        o1.x += a01.x; o1.y += a01.y; o1.z += a01.z; o1.w += a01.w;
        xp[0] = o0; xp[1] = o1;
    }
    if (n0 + r + 32 < N_NODES) {
        float4* xp = reinterpret_cast<float4*>(xi + (size_t)(n0 + r + 32) * 64 + kg * 8);
        float4 o0 = xp[0], o1 = xp[1];
        o0.x += a10.x; o0.y += a10.y; o0.z += a10.z; o0.w += a10.w;
        o1.x += a11.x; o1.y += a11.y; o1.z += a11.z; o1.w += a11.w;
        xp[0] = o0; xp[1] = o1;
    }
}

// ---------------------------------------------------------------------------
extern "C" void kernel_launch(void* const* d_in, const int* in_sizes, int n_in,
                              void* d_out, int out_size, void* d_ws, size_t ws_size,
                              hipStream_t stream) {
    const int*   species = (const int*)d_in[0];
    const int*   esrc    = (const int*)d_in[1];
    const int*   edst    = (const int*)d_in[2];
    const float* dist    = (const float*)d_in[3];
    const float* sw      = (const float*)d_in[4];
    const float* bo      = (const float*)d_in[5];
    const float* Wsp     = (const float*)d_in[6];
    const float* Wl      = (const float*)d_in[7];
    const float* bl      = (const float*)d_in[8];
    const float* fcW1    = (const float*)d_in[9];
    const float* fcb1    = (const float*)d_in[10];
    const float* fcW2    = (const float*)d_in[11];
    const float* fcb2    = (const float*)d_in[12];
    const float* fcW3    = (const float*)d_in[13];
    const float* fcb3    = (const float*)d_in[14];
    float* xi = (float*)d_out;

    char* ws = (char*)d_ws;
    float*        rb_sw = (float*)ws;                       //  5,120,000 B
    int*          rowp  = (int*)(ws + 5120000);             //     80,128 B
    float*        h     = (float*)(ws + 5200128);           //  2,560,000 B
    unsigned int* agg   = (unsigned int*)(ws + 7760128);    // 25,600,000 B (bf16)

    hipLaunchKernelGGL(edge_rb_kernel, dim3(625), dim3(256), 0, stream,
                       dist, sw, rb_sw);
    hipLaunchKernelGGL(row_start_kernel, dim3(79), dim3(256), 0, stream,
                       esrc, rowp);
    hipLaunchKernelGGL(xi_init_kernel, dim3(1250), dim3(256), 0, stream,
                       species, Wsp, xi);

    for (int l = 0; l < 3; ++l) {
        hipLaunchKernelGGL(h_kernel, dim3(625), dim3(256), 0, stream,
                           xi, Wl + (size_t)l * 64 * 32, bl + (size_t)l * 32, h);
        hipLaunchKernelGGL(agg_kernel, dim3(5000), dim3(256), 0, stream,
                           rb_sw, bo, rowp, edst, h, agg);
        hipLaunchKernelGGL(fc_kernel, dim3(313), dim3(256), 0, stream,
                           agg, h,
                           fcW1 + (size_t)l * 656 * 64, fcb1 + (size_t)l * 64,
                           fcW2 + (size_t)l * 64 * 64,  fcb2 + (size_t)l * 64,
                           fcW3 + (size_t)l * 64 * 64,  fcb3 + (size_t)l * 64,
                           xi);
    }
}

// Round 3
// 284.560 us; speedup vs baseline: 2.9188x; 2.9188x over previous
//
#include <hip/hip_runtime.h>
#include <math.h>

#define N_NODES 20000
#define N_EDGES 160000

#define PI_F 3.14159265358979323846f
#define LN2_F 0.69314718055994530942f

#define XSTR 656           // X row stride in bf16 elems (16B-aligned rows: 1312 B)
#define W1PK 43008         // 21 ksteps * 4 colfrags * 64 lanes * 8 (ushort units)
#define W23PK 4096         // 2 ksteps  * 4 * 64 * 8
#define WPK_LAYER 51200    // per-layer packed weights (ushort units)

typedef short short8v __attribute__((ext_vector_type(8)));
typedef float f32x4 __attribute__((ext_vector_type(4)));
typedef unsigned short u16;

__device__ __forceinline__ float sspf(float x) {
    return fmaxf(x, 0.0f) + log1pf(expf(-fabsf(x))) - LN2_F;
}
// round-to-nearest-even f32 -> bf16
__device__ __forceinline__ u16 f2bf(float f) {
    unsigned int u = __float_as_uint(f);
    return (u16)((u + 0x7fffu + ((u >> 16) & 1u)) >> 16);
}
__device__ __forceinline__ float bflo(unsigned int u) { return __uint_as_float(u << 16); }
__device__ __forceinline__ float bfhi(unsigned int u) { return __uint_as_float(u & 0xffff0000u); }

// ---------------------------------------------------------------------------
// rb_pk[e] = bf16x8 of switch[e] * sqrt(2/5) * sin((n+1) pi r / 5) / r
// ---------------------------------------------------------------------------
__global__ __launch_bounds__(256) void edge_rb_kernel(
    const float* __restrict__ dist,
    const float* __restrict__ sw,
    unsigned int* __restrict__ rbpk)   // E x 4 uints
{
    int e = blockIdx.x * blockDim.x + threadIdx.x;
    if (e >= N_EDGES) return;
    float r = dist[e];
    float c = sqrtf(2.0f / 5.0f) / r * sw[e];
    float out[8];
    #pragma unroll
    for (int n = 0; n < 8; ++n)
        out[n] = c * sinf((float)(n + 1) * PI_F * r * 0.2f);
    uint4 pk;
    pk.x = (unsigned int)f2bf(out[0]) | ((unsigned int)f2bf(out[1]) << 16);
    pk.y = (unsigned int)f2bf(out[2]) | ((unsigned int)f2bf(out[3]) << 16);
    pk.z = (unsigned int)f2bf(out[4]) | ((unsigned int)f2bf(out[5]) << 16);
    pk.w = (unsigned int)f2bf(out[6]) | ((unsigned int)f2bf(out[7]) << 16);
    *reinterpret_cast<uint4*>(rbpk + (size_t)e * 4) = pk;
}

// ---------------------------------------------------------------------------
// CSR offsets from sorted edge_src
// ---------------------------------------------------------------------------
__global__ __launch_bounds__(256) void row_start_kernel(
    const int* __restrict__ src, int* __restrict__ row)
{
    int i = blockIdx.x * blockDim.x + threadIdx.x;
    if (i > N_NODES) return;
    int lo = 0, hi = N_EDGES;
    while (lo < hi) {
        int mid = (lo + hi) >> 1;
        if (src[mid] < i) lo = mid + 1; else hi = mid;
    }
    row[i] = lo;
}

// ---------------------------------------------------------------------------
// xi = W_species[species]
// ---------------------------------------------------------------------------
__global__ __launch_bounds__(256) void xi_init_kernel(
    const int* __restrict__ species,
    const float* __restrict__ Wsp,
    float* __restrict__ xi)
{
    int idx = blockIdx.x * blockDim.x + threadIdx.x;
    if (idx >= N_NODES * 16) return;
    int node = idx >> 4;
    int c4 = idx & 15;
    int sp = species[node];
    reinterpret_cast<float4*>(xi)[idx] =
        reinterpret_cast<const float4*>(Wsp + (size_t)sp * 64)[c4];
}

// ---------------------------------------------------------------------------
// Pack FC weights -> bf16 B-fragment layout for mfma_f32_16x16x32_bf16.
// Element e of a pack: j = e&7, lane = (e>>3)&63, c16 = (e>>9)&3, ks = e>>11.
//   k = ks*32 + (lane>>4)*8 + j ; col = c16*16 + (lane&15)
// W1 rows permuted: X feature f = s*40+n*5+b  <->  orig row n*80+s*5+b.
// k in [640,656) -> si rows; k >= 656 -> zero (covers the K=672 overhang).
// ---------------------------------------------------------------------------
__global__ __launch_bounds__(256) void pack_w_kernel(
    const float* __restrict__ fcW1,
    const float* __restrict__ fcW2,
    const float* __restrict__ fcW3,
    u16* __restrict__ Wpk)
{
    int idx = blockIdx.x * 256 + threadIdx.x;
    if (idx >= 3 * WPK_LAYER) return;
    int layer = idx / WPK_LAYER;
    int r = idx - layer * WPK_LAYER;
    float val = 0.0f;
    if (r < W1PK) {
        int e = r;
        int j = e & 7, lane = (e >> 3) & 63, c16 = (e >> 9) & 3, ks = e >> 11;
        int k = ks * 32 + (lane >> 4) * 8 + j;
        int colm = c16 * 16 + (lane & 15);
        if (k < 640) {
            int ss = k / 40, rem = k - ss * 40;
            int nn = rem / 5, bb = rem - nn * 5;
            val = fcW1[(size_t)layer * 656 * 64 + (size_t)(nn * 80 + ss * 5 + bb) * 64 + colm];
        } else if (k < 656) {
            val = fcW1[(size_t)layer * 656 * 64 + (size_t)k * 64 + colm];
        }
    } else {
        bool is2 = (r < W1PK + W23PK);
        const float* W = is2 ? fcW2 : fcW3;
        int e = is2 ? (r - W1PK) : (r - W1PK - W23PK);
        int j = e & 7, lane = (e >> 3) & 63, c16 = (e >> 9) & 3, ks = e >> 11;
        int k = ks * 32 + (lane >> 4) * 8 + j;
        int colm = c16 * 16 + (lane & 15);
        val = W[(size_t)layer * 64 * 64 + (size_t)k * 64 + colm];
    }
    Wpk[(size_t)layer * WPK_LAYER + r] = f2bf(val);
}

// ---------------------------------------------------------------------------
// h = xi @ Wl[l] + bl[l]   (N x 32)
// ---------------------------------------------------------------------------
__global__ __launch_bounds__(256) void h_kernel(
    const float* __restrict__ xi,
    const float* __restrict__ Wl,
    const float* __restrict__ bl,
    float* __restrict__ h)
{
    __shared__ float xs[32 * 64];
    __shared__ float ws[64 * 32];
    int tid = threadIdx.x;
    int nb = blockIdx.x * 32;

    const float4* xsrc = reinterpret_cast<const float4*>(xi + (size_t)nb * 64);
    float4* xd = reinterpret_cast<float4*>(xs);
    #pragma unroll
    for (int i = 0; i < 2; ++i) xd[tid + i * 256] = xsrc[tid + i * 256];
    const float4* wsrc = reinterpret_cast<const float4*>(Wl);
    float4* wd = reinterpret_cast<float4*>(ws);
    #pragma unroll
    for (int i = 0; i < 2; ++i) wd[tid + i * 256] = wsrc[tid + i * 256];
    __syncthreads();

    int c = tid & 31;
    int ng = tid >> 5;
    float bias = bl[c];
    float acc[4] = {bias, bias, bias, bias};
    for (int j = 0; j < 64; ++j) {
        float wv = ws[j * 32 + c];
        #pragma unroll
        for (int q = 0; q < 4; ++q)
            acc[q] = fmaf(xs[(ng * 4 + q) * 64 + j], wv, acc[q]);
    }
    #pragma unroll
    for (int q = 0; q < 4; ++q)
        h[(size_t)(nb + ng * 4 + q) * 32 + c] = acc[q];
}

// ---------------------------------------------------------------------------
// Aggregation: one wave per node. lane = (es 0..3)<<4 | (s 0..15).
// Stores bf16 X row in permuted feature order f = s*40 + n*5 + b, plus
// si (h[:, :16]) into cols 640..655.
// ---------------------------------------------------------------------------
__global__ __launch_bounds__(256) void agg_kernel(
    const unsigned int* __restrict__ rbpk,  // E x 4 (bf16 pairs)
    const float* __restrict__ bo,           // E x 5
    const int* __restrict__ row,
    const int* __restrict__ dst,
    const float* __restrict__ h,            // N x 32
    u16* __restrict__ X)                    // N x 656 (bf16)
{
    int wid = (blockIdx.x * 256 + threadIdx.x) >> 6;
    if (wid >= N_NODES) return;
    int lane = threadIdx.x & 63;
    int s = lane & 15;
    int es = lane >> 4;

    int e0 = row[wid], e1 = row[wid + 1];

    float acc[40];
    #pragma unroll
    for (int j = 0; j < 40; ++j) acc[j] = 0.0f;

    for (int e = e0 + es; e < e1; e += 4) {
        int d = dst[e];
        float mi = h[(size_t)d * 32 + 16 + s];
        uint4 rv = *reinterpret_cast<const uint4*>(rbpk + (size_t)e * 4);
        const float* bp = bo + (size_t)e * 5;
        float bm0 = bp[0] * mi, bm1 = bp[1] * mi, bm2 = bp[2] * mi,
              bm3 = bp[3] * mi, bm4 = bp[4] * mi;
        float rr[8] = {bflo(rv.x), bfhi(rv.x), bflo(rv.y), bfhi(rv.y),
                       bflo(rv.z), bfhi(rv.z), bflo(rv.w), bfhi(rv.w)};
        #pragma unroll
        for (int n = 0; n < 8; ++n) {
            acc[n * 5 + 0] = fmaf(rr[n], bm0, acc[n * 5 + 0]);
            acc[n * 5 + 1] = fmaf(rr[n], bm1, acc[n * 5 + 1]);
            acc[n * 5 + 2] = fmaf(rr[n], bm2, acc[n * 5 + 2]);
            acc[n * 5 + 3] = fmaf(rr[n], bm3, acc[n * 5 + 3]);
            acc[n * 5 + 4] = fmaf(rr[n], bm4, acc[n * 5 + 4]);
        }
    }
    #pragma unroll
    for (int j = 0; j < 40; ++j) {
        acc[j] += __shfl_xor(acc[j], 16, 64);
        acc[j] += __shfl_xor(acc[j], 32, 64);
    }
    // lane (es,s) stores features f = s*40 + es*10 + {0..9} as 5 bf16 pairs
    unsigned int* outp = reinterpret_cast<unsigned int*>(X + (size_t)wid * XSTR)
                         + (s * 20 + es * 5);
    #pragma unroll
    for (int m = 0; m < 5; ++m) {
        int j = es * 10 + 2 * m;
        outp[m] = (unsigned int)f2bf(acc[j]) |
                  ((unsigned int)f2bf(acc[j + 1]) << 16);
    }
    // si: cols 640..655
    if (es == 2)
        X[(size_t)wid * XSTR + 640 + s] = f2bf(h[(size_t)wid * 32 + s]);
}

// ---------------------------------------------------------------------------
// Fused FC chain via MFMA. Block = 256 thr = 4 waves; 16 nodes per block.
// Wave w owns col-fragment w (cols 16w..16w+15). Fragment roles:
//   A: lane l -> row l&15, k = (l>>4)*8 + j          (16B load)
//   B: lane l -> col l&15, k = (l>>4)*8 + j          (packed, coalesced)
//   C: lane l -> col l&15, row = (l>>4)*4 + reg      [m89-verified]
// ---------------------------------------------------------------------------
__global__ __launch_bounds__(256) void fc_kernel(
    const u16* __restrict__ X,      // N x 656 bf16
    const u16* __restrict__ Wpk,    // layer's packed weights
    const float* __restrict__ b1,
    const float* __restrict__ b2,
    const float* __restrict__ b3,
    float* __restrict__ xi)
{
    __shared__ __align__(16) u16 Y1[16 * 72];
    __shared__ __align__(16) u16 Y2[16 * 72];

    int tid = threadIdx.x;
    int w = tid >> 6;
    int l = tid & 63;
    int lrow = l & 15;
    int lk = l >> 4;
    int n0 = blockIdx.x * 16;
    int node = n0 + lrow;
    int col = w * 16 + lrow;

    const u16* Wpk1 = Wpk;
    const u16* Wpk2 = Wpk + W1PK;
    const u16* Wpk3 = Wpk + W1PK + W23PK;

    // ---- FC1: K = 656 (+16 zero-padded via packed-W zeros) ----
    f32x4 acc;
    {
        float bv = b1[col];
        acc[0] = bv; acc[1] = bv; acc[2] = bv; acc[3] = bv;
    }
    const u16* xp = X + (size_t)node * XSTR + lk * 8;
    const u16* wp = Wpk1 + ((size_t)w * 64 + l) * 8;
    #pragma unroll
    for (int ks = 0; ks < 21; ++ks) {
        short8v a = *reinterpret_cast<const short8v*>(xp + ks * 32);
        short8v b = *reinterpret_cast<const short8v*>(wp + (size_t)ks * 2048);
        acc = __builtin_amdgcn_mfma_f32_16x16x32_bf16(a, b, acc, 0, 0, 0);
    }
    #pragma unroll
    for (int q = 0; q < 4; ++q)
        Y1[(lk * 4 + q) * 72 + col] = f2bf(sspf(acc[q]));
    __syncthreads();

    // ---- FC2: K = 64 ----
    {
        float bv = b2[col];
        acc[0] = bv; acc[1] = bv; acc[2] = bv; acc[3] = bv;
    }
    #pragma unroll
    for (int ks = 0; ks < 2; ++ks) {
        short8v a = *reinterpret_cast<const short8v*>(&Y1[lrow * 72 + ks * 32 + lk * 8]);
        short8v b = *reinterpret_cast<const short8v*>(Wpk2 + ((size_t)(ks * 4 + w) * 64 + l) * 8);
        acc = __builtin_amdgcn_mfma_f32_16x16x32_bf16(a, b, acc, 0, 0, 0);
    }
    #pragma unroll
    for (int q = 0; q < 4; ++q)
        Y2[(lk * 4 + q) * 72 + col] = f2bf(sspf(acc[q]));
    __syncthreads();

    // ---- FC3: K = 64, + residual ----
    {
        float bv = b3[col];
        acc[0] = bv; acc[1] = bv; acc[2] = bv; acc[3] = bv;
    }
    #pragma unroll
    for (int ks = 0; ks < 2; ++ks) {
        short8v a = *reinterpret_cast<const short8v*>(&Y2[lrow * 72 + ks * 32 + lk * 8]);
        short8v b = *reinterpret_cast<const short8v*>(Wpk3 + ((size_t)(ks * 4 + w) * 64 + l) * 8);
        acc = __builtin_amdgcn_mfma_f32_16x16x32_bf16(a, b, acc, 0, 0, 0);
    }
    #pragma unroll
    for (int q = 0; q < 4; ++q) {
        float* o = xi + (size_t)(n0 + lk * 4 + q) * 64 + col;
        *o += acc[q];
    }
}

// ---------------------------------------------------------------------------
extern "C" void kernel_launch(void* const* d_in, const int* in_sizes, int n_in,
                              void* d_out, int out_size, void* d_ws, size_t ws_size,
                              hipStream_t stream) {
    const int*   species = (const int*)d_in[0];
    const int*   esrc    = (const int*)d_in[1];
    const int*   edst    = (const int*)d_in[2];
    const float* dist    = (const float*)d_in[3];
    const float* sw      = (const float*)d_in[4];
    const float* bo      = (const float*)d_in[5];
    const float* Wsp     = (const float*)d_in[6];
    const float* Wl      = (const float*)d_in[7];
    const float* bl      = (const float*)d_in[8];
    const float* fcW1    = (const float*)d_in[9];
    const float* fcb1    = (const float*)d_in[10];
    const float* fcW2    = (const float*)d_in[11];
    const float* fcb2    = (const float*)d_in[12];
    const float* fcW3    = (const float*)d_in[13];
    const float* fcb3    = (const float*)d_in[14];
    float* xi = (float*)d_out;

    char* ws = (char*)d_ws;
    unsigned int* rbpk = (unsigned int*)ws;            //  2,560,000 B
    int*          rowp = (int*)(ws + 2560000);         //     80,128 B
    float*        h    = (float*)(ws + 2640128);       //  2,560,000 B
    u16*          X    = (u16*)(ws + 5200128);         // 26,240,064 B (+slack)
    u16*          Wpk  = (u16*)(ws + 31440192);        //    307,200 B
    // total ~31.75 MB

    hipLaunchKernelGGL(edge_rb_kernel, dim3(625), dim3(256), 0, stream,
                       dist, sw, rbpk);
    hipLaunchKernelGGL(row_start_kernel, dim3(79), dim3(256), 0, stream,
                       esrc, rowp);
    hipLaunchKernelGGL(xi_init_kernel, dim3(1250), dim3(256), 0, stream,
                       species, Wsp, xi);
    hipLaunchKernelGGL(pack_w_kernel, dim3(600), dim3(256), 0, stream,
                       fcW1, fcW2, fcW3, Wpk);

    for (int l = 0; l < 3; ++l) {
        hipLaunchKernelGGL(h_kernel, dim3(625), dim3(256), 0, stream,
                           xi, Wl + (size_t)l * 64 * 32, bl + (size_t)l * 32, h);
        hipLaunchKernelGGL(agg_kernel, dim3(5000), dim3(256), 0, stream,
                           rbpk, bo, rowp, edst, h, X);
        hipLaunchKernelGGL(fc_kernel, dim3(1250), dim3(256), 0, stream,
                           X, Wpk + (size_t)l * WPK_LAYER,
                           fcb1 + (size_t)l * 64, fcb2 + (size_t)l * 64,
                           fcb3 + (size_t)l * 64, xi);
    }
}

// Round 4
// 281.071 us; speedup vs baseline: 2.9550x; 1.0124x over previous
//
#include <hip/hip_runtime.h>
#include <math.h>

#define N_NODES 20000
#define N_EDGES 160000

#define PI_F 3.14159265358979323846f
#define LN2_F 0.69314718055994530942f

#define XSTR 656           // X row stride in bf16 elems (1312 B rows, 16B aligned)
#define W1PK 43008         // 21 ksteps * 4 colfrags * 64 lanes * 8 (ushort units)
#define W23PK 4096         // 2 ksteps  * 4 * 64 * 8
#define WPK_LAYER 51200    // per-layer packed weights (ushort units)

typedef short short8v __attribute__((ext_vector_type(8)));
typedef float f32x4 __attribute__((ext_vector_type(4)));
typedef unsigned short u16;

__device__ __forceinline__ float sspf(float x) {
    return fmaxf(x, 0.0f) + log1pf(expf(-fabsf(x))) - LN2_F;
}
// round-to-nearest-even f32 -> bf16
__device__ __forceinline__ u16 f2bf(float f) {
    unsigned int u = __float_as_uint(f);
    return (u16)((u + 0x7fffu + ((u >> 16) & 1u)) >> 16);
}
__device__ __forceinline__ float bflo(unsigned int u) { return __uint_as_float(u << 16); }
__device__ __forceinline__ float bfhi(unsigned int u) { return __uint_as_float(u & 0xffff0000u); }

// ---------------------------------------------------------------------------
// rb_pk[e] = bf16x8 of switch[e] * sqrt(2/5) * sin((n+1) pi r / 5) / r
// ---------------------------------------------------------------------------
__global__ __launch_bounds__(256) void edge_rb_kernel(
    const float* __restrict__ dist,
    const float* __restrict__ sw,
    unsigned int* __restrict__ rbpk)   // E x 4 uints
{
    int e = blockIdx.x * blockDim.x + threadIdx.x;
    if (e >= N_EDGES) return;
    float r = dist[e];
    float c = sqrtf(2.0f / 5.0f) / r * sw[e];
    float out[8];
    #pragma unroll
    for (int n = 0; n < 8; ++n)
        out[n] = c * sinf((float)(n + 1) * PI_F * r * 0.2f);
    uint4 pk;
    pk.x = (unsigned int)f2bf(out[0]) | ((unsigned int)f2bf(out[1]) << 16);
    pk.y = (unsigned int)f2bf(out[2]) | ((unsigned int)f2bf(out[3]) << 16);
    pk.z = (unsigned int)f2bf(out[4]) | ((unsigned int)f2bf(out[5]) << 16);
    pk.w = (unsigned int)f2bf(out[6]) | ((unsigned int)f2bf(out[7]) << 16);
    *reinterpret_cast<uint4*>(rbpk + (size_t)e * 4) = pk;
}

// ---------------------------------------------------------------------------
// CSR offsets from sorted edge_src
// ---------------------------------------------------------------------------
__global__ __launch_bounds__(256) void row_start_kernel(
    const int* __restrict__ src, int* __restrict__ row)
{
    int i = blockIdx.x * blockDim.x + threadIdx.x;
    if (i > N_NODES) return;
    int lo = 0, hi = N_EDGES;
    while (lo < hi) {
        int mid = (lo + hi) >> 1;
        if (src[mid] < i) lo = mid + 1; else hi = mid;
    }
    row[i] = lo;
}

// ---------------------------------------------------------------------------
// xi = W_species[species]
// ---------------------------------------------------------------------------
__global__ __launch_bounds__(256) void xi_init_kernel(
    const int* __restrict__ species,
    const float* __restrict__ Wsp,
    float* __restrict__ xi)
{
    int idx = blockIdx.x * blockDim.x + threadIdx.x;
    if (idx >= N_NODES * 16) return;
    int node = idx >> 4;
    int c4 = idx & 15;
    int sp = species[node];
    reinterpret_cast<float4*>(xi)[idx] =
        reinterpret_cast<const float4*>(Wsp + (size_t)sp * 64)[c4];
}

// ---------------------------------------------------------------------------
// Pack FC weights -> bf16 B-fragment layout for mfma_f32_16x16x32_bf16.
// ---------------------------------------------------------------------------
__global__ __launch_bounds__(256) void pack_w_kernel(
    const float* __restrict__ fcW1,
    const float* __restrict__ fcW2,
    const float* __restrict__ fcW3,
    u16* __restrict__ Wpk)
{
    int idx = blockIdx.x * 256 + threadIdx.x;
    if (idx >= 3 * WPK_LAYER) return;
    int layer = idx / WPK_LAYER;
    int r = idx - layer * WPK_LAYER;
    float val = 0.0f;
    if (r < W1PK) {
        int e = r;
        int j = e & 7, lane = (e >> 3) & 63, c16 = (e >> 9) & 3, ks = e >> 11;
        int k = ks * 32 + (lane >> 4) * 8 + j;
        int colm = c16 * 16 + (lane & 15);
        if (k < 640) {
            int ss = k / 40, rem = k - ss * 40;
            int nn = rem / 5, bb = rem - nn * 5;
            val = fcW1[(size_t)layer * 656 * 64 + (size_t)(nn * 80 + ss * 5 + bb) * 64 + colm];
        } else if (k < 656) {
            val = fcW1[(size_t)layer * 656 * 64 + (size_t)k * 64 + colm];
        }
    } else {
        bool is2 = (r < W1PK + W23PK);
        const float* W = is2 ? fcW2 : fcW3;
        int e = is2 ? (r - W1PK) : (r - W1PK - W23PK);
        int j = e & 7, lane = (e >> 3) & 63, c16 = (e >> 9) & 3, ks = e >> 11;
        int k = ks * 32 + (lane >> 4) * 8 + j;
        int colm = c16 * 16 + (lane & 15);
        val = W[(size_t)layer * 64 * 64 + (size_t)k * 64 + colm];
    }
    Wpk[(size_t)layer * WPK_LAYER + r] = f2bf(val);
}

// ---------------------------------------------------------------------------
// h = xi @ Wl[l] + bl[l]   (N x 32)
// ---------------------------------------------------------------------------
__global__ __launch_bounds__(256) void h_kernel(
    const float* __restrict__ xi,
    const float* __restrict__ Wl,
    const float* __restrict__ bl,
    float* __restrict__ h)
{
    __shared__ float xs[32 * 64];
    __shared__ float ws[64 * 32];
    int tid = threadIdx.x;
    int nb = blockIdx.x * 32;

    const float4* xsrc = reinterpret_cast<const float4*>(xi + (size_t)nb * 64);
    float4* xd = reinterpret_cast<float4*>(xs);
    #pragma unroll
    for (int i = 0; i < 2; ++i) xd[tid + i * 256] = xsrc[tid + i * 256];
    const float4* wsrc = reinterpret_cast<const float4*>(Wl);
    float4* wd = reinterpret_cast<float4*>(ws);
    #pragma unroll
    for (int i = 0; i < 2; ++i) wd[tid + i * 256] = wsrc[tid + i * 256];
    __syncthreads();

    int c = tid & 31;
    int ng = tid >> 5;
    float bias = bl[c];
    float acc[4] = {bias, bias, bias, bias};
    for (int j = 0; j < 64; ++j) {
        float wv = ws[j * 32 + c];
        #pragma unroll
        for (int q = 0; q < 4; ++q)
            acc[q] = fmaf(xs[(ng * 4 + q) * 64 + j], wv, acc[q]);
    }
    #pragma unroll
    for (int q = 0; q < 4; ++q)
        h[(size_t)(nb + ng * 4 + q) * 32 + c] = acc[q];
}

// ---------------------------------------------------------------------------
// Aggregation: one wave per node. lane = (es 0..3)<<4 | (s 0..15).
// Accumulate, butterfly-reduce, STAGE the 1312B bf16 row in LDS, then write
// it out with full-wave contiguous dword stores (coalesced; kills the 12x
// partial-sector write amplification seen in R3).
// Row layout: f = s*40 + n*5 + b for f<640; cols 640..655 = si = h[:, :16].
// ---------------------------------------------------------------------------
__global__ __launch_bounds__(256) void agg_kernel(
    const unsigned int* __restrict__ rbpk,  // E x 4 (bf16 pairs)
    const float* __restrict__ bo,           // E x 5
    const int* __restrict__ row,
    const int* __restrict__ dst,
    const float* __restrict__ h,            // N x 32
    u16* __restrict__ X)                    // N x 656 (bf16)
{
    __shared__ unsigned int rowbuf[4][332];   // 328 dwords + pad

    int wv = threadIdx.x >> 6;                // wave in block
    int wid = (blockIdx.x << 2) | wv;         // node (grid is exact: 5000*4)
    int lane = threadIdx.x & 63;
    int s = lane & 15;
    int es = lane >> 4;

    int e0 = row[wid], e1 = row[wid + 1];

    float acc[40];
    #pragma unroll
    for (int j = 0; j < 40; ++j) acc[j] = 0.0f;

    for (int e = e0 + es; e < e1; e += 4) {
        int d = dst[e];
        float mi = h[(size_t)d * 32 + 16 + s];
        uint4 rv = *reinterpret_cast<const uint4*>(rbpk + (size_t)e * 4);
        const float* bp = bo + (size_t)e * 5;
        float bm0 = bp[0] * mi, bm1 = bp[1] * mi, bm2 = bp[2] * mi,
              bm3 = bp[3] * mi, bm4 = bp[4] * mi;
        float rr[8] = {bflo(rv.x), bfhi(rv.x), bflo(rv.y), bfhi(rv.y),
                       bflo(rv.z), bfhi(rv.z), bflo(rv.w), bfhi(rv.w)};
        #pragma unroll
        for (int n = 0; n < 8; ++n) {
            acc[n * 5 + 0] = fmaf(rr[n], bm0, acc[n * 5 + 0]);
            acc[n * 5 + 1] = fmaf(rr[n], bm1, acc[n * 5 + 1]);
            acc[n * 5 + 2] = fmaf(rr[n], bm2, acc[n * 5 + 2]);
            acc[n * 5 + 3] = fmaf(rr[n], bm3, acc[n * 5 + 3]);
            acc[n * 5 + 4] = fmaf(rr[n], bm4, acc[n * 5 + 4]);
        }
    }
    #pragma unroll
    for (int j = 0; j < 40; ++j) {
        acc[j] += __shfl_xor(acc[j], 16, 64);
        acc[j] += __shfl_xor(acc[j], 32, 64);
    }

    // ---- stage into LDS row buffer ----
    unsigned int* rb = rowbuf[wv];
    // lane (es,s): feature dwords s*20 + es*5 + {0..4}
    unsigned int* op = rb + (s * 20 + es * 5);
    #pragma unroll
    for (int m = 0; m < 5; ++m) {
        int j = es * 10 + 2 * m;
        op[m] = (unsigned int)f2bf(acc[j]) |
                ((unsigned int)f2bf(acc[j + 1]) << 16);
    }
    // si: dwords 320..327 (16 bf16 from h[wid, 0:16])
    if (es == 2 && s < 8) {
        float v0 = h[(size_t)wid * 32 + 2 * s];
        float v1 = h[(size_t)wid * 32 + 2 * s + 1];
        rb[320 + s] = (unsigned int)f2bf(v0) | ((unsigned int)f2bf(v1) << 16);
    }
    // same-wave LDS write->read: compiler inserts lgkmcnt; no barrier needed.

    // ---- coalesced write-out: 5 full-wave dword rounds + 8-dword tail ----
    unsigned int* Xrow = reinterpret_cast<unsigned int*>(X + (size_t)wid * XSTR);
    #pragma unroll
    for (int r = 0; r < 5; ++r)
        Xrow[r * 64 + lane] = rb[r * 64 + lane];
    if (lane < 8)
        Xrow[320 + lane] = rb[320 + lane];
}

// ---------------------------------------------------------------------------
// Fused FC chain via MFMA. Block = 256 thr = 4 waves; 16 nodes per block.
// ---------------------------------------------------------------------------
__global__ __launch_bounds__(256) void fc_kernel(
    const u16* __restrict__ X,      // N x 656 bf16
    const u16* __restrict__ Wpk,    // layer's packed weights
    const float* __restrict__ b1,
    const float* __restrict__ b2,
    const float* __restrict__ b3,
    float* __restrict__ xi)
{
    __shared__ __align__(16) u16 Y1[16 * 72];
    __shared__ __align__(16) u16 Y2[16 * 72];

    int tid = threadIdx.x;
    int w = tid >> 6;
    int l = tid & 63;
    int lrow = l & 15;
    int lk = l >> 4;
    int n0 = blockIdx.x * 16;
    int node = n0 + lrow;
    int col = w * 16 + lrow;

    const u16* Wpk1 = Wpk;
    const u16* Wpk2 = Wpk + W1PK;
    const u16* Wpk3 = Wpk + W1PK + W23PK;

    // ---- FC1: K = 656 (+16 zero-padded via packed-W zeros) ----
    f32x4 acc;
    {
        float bv = b1[col];
        acc[0] = bv; acc[1] = bv; acc[2] = bv; acc[3] = bv;
    }
    const u16* xp = X + (size_t)node * XSTR + lk * 8;
    const u16* wp = Wpk1 + ((size_t)w * 64 + l) * 8;
    #pragma unroll
    for (int ks = 0; ks < 21; ++ks) {
        short8v a = *reinterpret_cast<const short8v*>(xp + ks * 32);
        short8v b = *reinterpret_cast<const short8v*>(wp + (size_t)ks * 2048);
        acc = __builtin_amdgcn_mfma_f32_16x16x32_bf16(a, b, acc, 0, 0, 0);
    }
    #pragma unroll
    for (int q = 0; q < 4; ++q)
        Y1[(lk * 4 + q) * 72 + col] = f2bf(sspf(acc[q]));
    __syncthreads();

    // ---- FC2: K = 64 ----
    {
        float bv = b2[col];
        acc[0] = bv; acc[1] = bv; acc[2] = bv; acc[3] = bv;
    }
    #pragma unroll
    for (int ks = 0; ks < 2; ++ks) {
        short8v a = *reinterpret_cast<const short8v*>(&Y1[lrow * 72 + ks * 32 + lk * 8]);
        short8v b = *reinterpret_cast<const short8v*>(Wpk2 + ((size_t)(ks * 4 + w) * 64 + l) * 8);
        acc = __builtin_amdgcn_mfma_f32_16x16x32_bf16(a, b, acc, 0, 0, 0);
    }
    #pragma unroll
    for (int q = 0; q < 4; ++q)
        Y2[(lk * 4 + q) * 72 + col] = f2bf(sspf(acc[q]));
    __syncthreads();

    // ---- FC3: K = 64, + residual ----
    {
        float bv = b3[col];
        acc[0] = bv; acc[1] = bv; acc[2] = bv; acc[3] = bv;
    }
    #pragma unroll
    for (int ks = 0; ks < 2; ++ks) {
        short8v a = *reinterpret_cast<const short8v*>(&Y2[lrow * 72 + ks * 32 + lk * 8]);
        short8v b = *reinterpret_cast<const short8v*>(Wpk3 + ((size_t)(ks * 4 + w) * 64 + l) * 8);
        acc = __builtin_amdgcn_mfma_f32_16x16x32_bf16(a, b, acc, 0, 0, 0);
    }
    #pragma unroll
    for (int q = 0; q < 4; ++q) {
        float* o = xi + (size_t)(n0 + lk * 4 + q) * 64 + col;
        *o += acc[q];
    }
}

// ---------------------------------------------------------------------------
extern "C" void kernel_launch(void* const* d_in, const int* in_sizes, int n_in,
                              void* d_out, int out_size, void* d_ws, size_t ws_size,
                              hipStream_t stream) {
    const int*   species = (const int*)d_in[0];
    const int*   esrc    = (const int*)d_in[1];
    const int*   edst    = (const int*)d_in[2];
    const float* dist    = (const float*)d_in[3];
    const float* sw      = (const float*)d_in[4];
    const float* bo      = (const float*)d_in[5];
    const float* Wsp     = (const float*)d_in[6];
    const float* Wl      = (const float*)d_in[7];
    const float* bl      = (const float*)d_in[8];
    const float* fcW1    = (const float*)d_in[9];
    const float* fcb1    = (const float*)d_in[10];
    const float* fcW2    = (const float*)d_in[11];
    const float* fcb2    = (const float*)d_in[12];
    const float* fcW3    = (const float*)d_in[13];
    const float* fcb3    = (const float*)d_in[14];
    float* xi = (float*)d_out;

    char* ws = (char*)d_ws;
    unsigned int* rbpk = (unsigned int*)ws;            //  2,560,000 B
    int*          rowp = (int*)(ws + 2560000);         //     80,128 B
    float*        h    = (float*)(ws + 2640128);       //  2,560,000 B
    u16*          X    = (u16*)(ws + 5200128);         // 26,240,064 B (+slack)
    u16*          Wpk  = (u16*)(ws + 31440192);        //    307,200 B

    hipLaunchKernelGGL(edge_rb_kernel, dim3(625), dim3(256), 0, stream,
                       dist, sw, rbpk);
    hipLaunchKernelGGL(row_start_kernel, dim3(79), dim3(256), 0, stream,
                       esrc, rowp);
    hipLaunchKernelGGL(xi_init_kernel, dim3(1250), dim3(256), 0, stream,
                       species, Wsp, xi);
    hipLaunchKernelGGL(pack_w_kernel, dim3(600), dim3(256), 0, stream,
                       fcW1, fcW2, fcW3, Wpk);

    for (int l = 0; l < 3; ++l) {
        hipLaunchKernelGGL(h_kernel, dim3(625), dim3(256), 0, stream,
                           xi, Wl + (size_t)l * 64 * 32, bl + (size_t)l * 32, h);
        hipLaunchKernelGGL(agg_kernel, dim3(5000), dim3(256), 0, stream,
                           rbpk, bo, rowp, edst, h, X);
        hipLaunchKernelGGL(fc_kernel, dim3(1250), dim3(256), 0, stream,
                           X, Wpk + (size_t)l * WPK_LAYER,
                           fcb1 + (size_t)l * 64, fcb2 + (size_t)l * 64,
                           fcb3 + (size_t)l * 64, xi);
    }
}